// Round 6
// baseline (19381.206 us; speedup 1.0000x reference)
//
#include <hip/hip_runtime.h>

typedef unsigned short u16;
typedef unsigned long long u64;
typedef __attribute__((ext_vector_type(8))) short bf16x8;
typedef __attribute__((ext_vector_type(4))) float f32x4;

#define BSZ 32
#define TT 512
#define GG (BSZ*TT)      // 16384
#define NNODE 64
#define EE 126
#define H8 1024
#define H3 3072
#define NWG2 32          // enc_rec2 workgroups

__device__ __forceinline__ float b2f(u16 u){
  union { unsigned i; float f; } v; v.i = ((unsigned)u) << 16; return v.f;
}
__device__ __forceinline__ u16 f2b(float f){
  unsigned i = __float_as_uint(f);
  unsigned r = (i + 0x7FFFu + ((i >> 16) & 1u)) >> 16;   // RNE
  return (u16)r;
}
__device__ __forceinline__ float sigm(float x){ return 1.f/(1.f+__expf(-x)); }
__device__ __forceinline__ float tanh_f(float x){
  float xc = fminf(fmaxf(x, -15.f), 15.f);
  float e = __expf(2.f*xc);
  return (e-1.f)/(e+1.f);
}
__device__ __forceinline__ int prow(int m, int perm){
  return perm ? ((m & (TT-1))*BSZ + (m >> 9)) : m;
}
__device__ __forceinline__ u64 aload64(const u64* p){
  return __hip_atomic_load(p, __ATOMIC_RELAXED, __HIP_MEMORY_SCOPE_AGENT);
}

// ---------------- dtype detection: *flag = 1 if inputs are fp32 ----------------
__global__ __launch_bounds__(256) void detect_dtype(const void* xraw, int* flag){
  __shared__ int cnt;
  if (threadIdx.x == 0) cnt = 0;
  __syncthreads();
  const u16* p = (const u16*)xraw;
  u16 u = p[2*threadIdx.x];
  int e = (u >> 7) & 0xFF;
  int weird = (e < 100 || e > 134) ? 1 : 0;
  atomicAdd(&cnt, weird);
  __syncthreads();
  if (threadIdx.x == 0) *flag = (cnt > 128) ? 1 : 0;
}

__global__ __launch_bounds__(256) void cvt_bf16(const void* __restrict__ in,
                                                u16* __restrict__ out, int n,
                                                const int* __restrict__ flag){
  int i = blockIdx.x*256 + threadIdx.x;
  if (i >= n) return;
  if (*flag) out[i] = f2b(((const float*)in)[i]);
  else       out[i] = ((const u16*)in)[i];
}

// ---------------- GCN ----------------
__global__ __launch_bounds__(64) void gcn_kernel(
    const u16* __restrict__ x, const int* __restrict__ ei,
    const u16* __restrict__ w1, const u16* __restrict__ b1,
    const u16* __restrict__ w2, const u16* __restrict__ b2,
    const u16* __restrict__ cw, const u16* __restrict__ cb,
    u16* __restrict__ res)
{
  __shared__ int se[EE], de[EE];
  __shared__ float dinv[NNODE];
  __shared__ float nrm[EE];
  __shared__ float hs[NNODE][4];
  const int n = threadIdx.x;
  const int g = blockIdx.x;
  for (int e = n; e < EE; e += 64){ se[e] = ei[e]; de[e] = ei[EE + e]; }
  __syncthreads();
  int cnt = 0;
  for (int e = 0; e < EE; e++) cnt += (de[e] == n) ? 1 : 0;
  float di = rsqrtf(1.0f + (float)cnt);
  dinv[n] = di;
  float x0 = b2f(x[((size_t)g*NNODE + n)*2 + 0]);
  float x1 = b2f(x[((size_t)g*NNODE + n)*2 + 1]);
  float hw[4];
  #pragma unroll
  for (int c = 0; c < 4; c++) hw[c] = x0*b2f(w1[c]) + x1*b2f(w1[4+c]);
  #pragma unroll
  for (int c = 0; c < 4; c++) hs[n][c] = hw[c];
  __syncthreads();
  for (int e = n; e < EE; e += 64) nrm[e] = dinv[se[e]] * dinv[de[e]];
  __syncthreads();
  float selfc = di*di;
  float agg[4];
  #pragma unroll
  for (int c = 0; c < 4; c++) agg[c] = hw[c]*selfc;
  for (int e = 0; e < EE; e++){
    if (de[e] == n){
      float w = nrm[e]; int s = se[e];
      #pragma unroll
      for (int c = 0; c < 4; c++) agg[c] += hs[s][c]*w;
    }
  }
  float h1[4];
  #pragma unroll
  for (int c = 0; c < 4; c++) h1[c] = tanh_f(agg[c] + b2f(b1[c]));
  __syncthreads();
  float hw2[2];
  #pragma unroll
  for (int c = 0; c < 2; c++){
    float s = 0.f;
    #pragma unroll
    for (int k = 0; k < 4; k++) s += h1[k]*b2f(w2[k*2+c]);
    hw2[c] = s;
    hs[n][c] = s;
  }
  __syncthreads();
  float agg2[2] = { hw2[0]*selfc, hw2[1]*selfc };
  for (int e = 0; e < EE; e++){
    if (de[e] == n){
      float w = nrm[e]; int s = se[e];
      agg2[0] += hs[s][0]*w;
      agg2[1] += hs[s][1]*w;
    }
  }
  float h2a = tanh_f(agg2[0] + b2f(b2[0]));
  float h2b = tanh_f(agg2[1] + b2f(b2[1]));
  #pragma unroll
  for (int c = 0; c < 2; c++){
    float o = h2a*b2f(cw[c]) + h2b*b2f(cw[2+c]) + b2f(cb[c]);
    res[(size_t)g*128 + n*2 + c] = f2b(o);
  }
}

// ---------------- bf16 transpose ----------------
__global__ __launch_bounds__(256) void transpose_bf16(
    const u16* __restrict__ in, u16* __restrict__ out, int R, int C)
{
  __shared__ u16 tile[32][33];
  int c0 = blockIdx.x*32, r0 = blockIdx.y*32;
  for (int i = threadIdx.y; i < 32; i += 8)
    tile[i][threadIdx.x] = in[(size_t)(r0+i)*C + c0 + threadIdx.x];
  __syncthreads();
  for (int i = threadIdx.y; i < 32; i += 8)
    out[(size_t)(c0+i)*R + r0 + threadIdx.x] = tile[threadIdx.x][i];
}

// ---------------- GEMM NT ----------------
__global__ __launch_bounds__(256) void gemm_nt(
    const u16* __restrict__ A, const u16* __restrict__ Bm,
    const u16* __restrict__ bias, void* __restrict__ C,
    int M, int N, int K, int relu, int permA, int permC,
    const int* __restrict__ outflag)
{
  const int wave = threadIdx.x >> 6;
  const int lane = threadIdx.x & 63;
  const int wm = wave >> 1, wn = wave & 1;
  const int q = lane >> 4, lr = lane & 15;
  const int mBase = blockIdx.y*128 + wm*64;
  const int nBase = blockIdx.x*128 + wn*64;
  f32x4 acc[4][4] = {};
  const u16* ap[4]; const u16* bp[4];
  #pragma unroll
  for (int i = 0; i < 4; i++){
    ap[i] = A + (size_t)prow(mBase + i*16 + lr, permA)*K + q*8;
    bp[i] = Bm + (size_t)(nBase + i*16 + lr)*K + q*8;
  }
  for (int kb = 0; kb < K; kb += 32){
    bf16x8 av[4], bv[4];
    #pragma unroll
    for (int i = 0; i < 4; i++){
      av[i] = *(const bf16x8*)ap[i]; bv[i] = *(const bf16x8*)bp[i];
      ap[i] += 32; bp[i] += 32;
    }
    #pragma unroll
    for (int mi = 0; mi < 4; mi++)
      #pragma unroll
      for (int ni = 0; ni < 4; ni++)
        acc[mi][ni] = __builtin_amdgcn_mfma_f32_16x16x32_bf16(av[mi], bv[ni], acc[mi][ni], 0, 0, 0);
  }
  const int of32 = outflag ? *outflag : 0;
  #pragma unroll
  for (int ni = 0; ni < 4; ni++){
    int col = nBase + ni*16 + lr;
    float bb = bias ? b2f(bias[col]) : 0.f;
    #pragma unroll
    for (int mi = 0; mi < 4; mi++){
      #pragma unroll
      for (int r = 0; r < 4; r++){
        int row = prow(mBase + mi*16 + q*4 + r, permC);
        float v = acc[mi][ni][r] + bb;
        if (relu) v = fmaxf(v, 0.f);
        size_t idx = (size_t)row*N + col;
        if (of32) ((float*)C)[idx] = v;
        else      ((u16*)C)[idx]   = f2b(v);
      }
    }
  }
}

// ---------------- encoder GRU recurrence v2 (H=1024) ----------------
// 32 WGs x 256 thr (4 waves). WG wg owns h-cols [wg*32, wg*32+32) x 3 gates.
// Wave w: jt = w>>1 (16-col tile), bh2 = w&1 (16-batch half), all 3 gates.
// Per step: h[t-1] cooperatively loaded into LDS (coalesced), ds_read_b128
// A-frags reused across gates; weights stream from L2 (768 KB/XCD resident);
// 32-arrival barrier (tid0 arrive+spin, others at s_barrier); gi prefetched
// between arrival and spin. h traffic = relaxed agent-scope atomics.
__global__ __launch_bounds__(256) void enc_rec2(
    const u16* __restrict__ gi,   // [TT*32, 3072] t-major (bih included)
    const u16* __restrict__ whh,  // [3072, 1024]
    const u16* __restrict__ bhh,  // [3072]
    u16* __restrict__ seq,        // out [TT*32, 1024] t-major
    int* __restrict__ cnt)        // [4*TT] sub-counters
{
  __shared__ u16 hbuf[32*1032];   // 32 batches x 1024 cols, row stride 1032 (+16B pad)
  const int wg = blockIdx.x;      // 0..31
  const int tid = threadIdx.x;
  const int w = tid >> 6, lane = tid & 63, q = lane >> 4, lr = lane & 15;
  const int jt = w >> 1, bh2 = w & 1;
  const int j = wg*32 + jt*16 + lr;
  const int bbase = bh2*16;
  const float bh_r = b2f(bhh[j]);
  const float bh_z = b2f(bhh[H8 + j]);
  const float bh_n = b2f(bhh[2*H8 + j]);
  const u16* wp0 = whh + (size_t)(0*H8 + j)*H8 + q*8;
  const u16* wp1 = whh + (size_t)(1*H8 + j)*H8 + q*8;
  const u16* wp2 = whh + (size_t)(2*H8 + j)*H8 + q*8;
  float hreg[4] = {0.f,0.f,0.f,0.f};
  u16 gpre[12];
  #pragma unroll
  for (int r = 0; r < 4; r++){
    size_t row = (size_t)(bbase + q*4 + r)*H3;
    gpre[r]   = gi[row + j];
    gpre[4+r] = gi[row + H8 + j];
    gpre[8+r] = gi[row + 2*H8 + j];
  }
  for (int t = 0; t < TT; t++){
    float gr_[4], gz_[4], gn_[4];
    #pragma unroll
    for (int r = 0; r < 4; r++){
      gr_[r] = b2f(gpre[r]); gz_[r] = b2f(gpre[4+r]); gn_[r] = b2f(gpre[8+r]);
    }
    f32x4 acc0 = {}, acc1 = {}, acc2 = {};
    if (t > 0){
      const u16* abase = hbuf + (size_t)(bbase + lr)*1032 + q*8;
      #pragma unroll 8
      for (int kb = 0; kb < 32; kb++){
        bf16x8 a  = *(const bf16x8*)(abase + kb*32);
        bf16x8 w0 = *(const bf16x8*)(wp0 + kb*32);
        bf16x8 w1 = *(const bf16x8*)(wp1 + kb*32);
        bf16x8 w2 = *(const bf16x8*)(wp2 + kb*32);
        acc0 = __builtin_amdgcn_mfma_f32_16x16x32_bf16(a, w0, acc0, 0,0,0);
        acc1 = __builtin_amdgcn_mfma_f32_16x16x32_bf16(a, w1, acc1, 0,0,0);
        acc2 = __builtin_amdgcn_mfma_f32_16x16x32_bf16(a, w2, acc2, 0,0,0);
      }
    }
    #pragma unroll
    for (int r = 0; r < 4; r++){
      float rr = sigm(gr_[r] + acc0[r] + bh_r);
      float zz = sigm(gz_[r] + acc1[r] + bh_z);
      float nn = tanh_f(gn_[r] + rr*(acc2[r] + bh_n));
      float hnew = (1.f - zz)*nn + zz*hreg[r];
      hreg[r] = hnew;
      __hip_atomic_store(&seq[(size_t)(t*BSZ + bbase + q*4 + r)*H8 + j], f2b(hnew),
                         __ATOMIC_RELAXED, __HIP_MEMORY_SCOPE_AGENT);
    }
    asm volatile("s_waitcnt vmcnt(0)" ::: "memory");   // this wave's h stores done
    __syncthreads();                                    // whole WG's h stores done
    if (tid == 0)
      __hip_atomic_fetch_add(&cnt[(wg & 3)*TT + t], 1, __ATOMIC_RELAXED, __HIP_MEMORY_SCOPE_AGENT);
    if (t + 1 < TT){
      // prefetch next gi (lands during the spin)
      #pragma unroll
      for (int r = 0; r < 4; r++){
        size_t row = (size_t)((t+1)*BSZ + bbase + q*4 + r)*H3;
        gpre[r]   = gi[row + j];
        gpre[4+r] = gi[row + H8 + j];
        gpre[8+r] = gi[row + 2*H8 + j];
      }
      if (tid == 0){
        for (;;){
          int s = 0;
          #pragma unroll
          for (int i = 0; i < 4; i++)
            s += __hip_atomic_load(&cnt[i*TT + t], __ATOMIC_RELAXED, __HIP_MEMORY_SCOPE_AGENT);
          if (s == NWG2) break;
          __builtin_amdgcn_s_sleep(1);
        }
      }
      __syncthreads();   // release all waves after spin
      // cooperative load of h[t] (32x1024) into LDS, coalesced 16B chunks
      const u64* src = (const u64*)(seq + (size_t)t*BSZ*H8);
      #pragma unroll
      for (int i = 0; i < 16; i++){
        int c = i*256 + tid;          // chunk id: 32 b x 128 kc
        int b = c >> 7, kc = c & 127;
        u64 lo = aload64(src + (size_t)b*256 + kc*2);
        u64 hi = aload64(src + (size_t)b*256 + kc*2 + 1);
        u64* dst = (u64*)(hbuf + (size_t)b*1032 + kc*8);
        dst[0] = lo; dst[1] = hi;
      }
      __syncthreads();   // LDS h ready for next step
    }
  }
}

// ---------------- decoder GRU recurrence (H=128), round-4 version ----------------
// 2 WGs x 256 thr; WG = 16 batches. whh in REGISTERS; LDS = h history;
// gi in [t][b] layout, prefetched one step ahead.
__global__ __launch_bounds__(256) void dec_rec(
    const u16* __restrict__ gi,   // [TT*32, 384] t-major (bih included)
    const u16* __restrict__ whh,  // [384, 128]
    const u16* __restrict__ bhh,  // [384]
    u16* __restrict__ seq)        // out [TT*32, 128] t-major
{
  __shared__ u16 hlds[16*136];
  const int bb = blockIdx.x*16;
  const int tid = threadIdx.x;
  const int w = tid >> 6, lane = tid & 63, q = lane >> 4, lr = lane & 15;
  bf16x8 wreg[3][2][4];
  #pragma unroll
  for (int g2 = 0; g2 < 3; g2++)
    #pragma unroll
    for (int nt = 0; nt < 2; nt++){
      int jj = g2*128 + w*32 + nt*16 + lr;
      #pragma unroll
      for (int kb = 0; kb < 4; kb++)
        wreg[g2][nt][kb] = *(const bf16x8*)(whh + (size_t)jj*128 + kb*32 + q*8);
    }
  float bh[3][2];
  #pragma unroll
  for (int g2 = 0; g2 < 3; g2++)
    #pragma unroll
    for (int nt = 0; nt < 2; nt++)
      bh[g2][nt] = b2f(bhh[g2*128 + w*32 + nt*16 + lr]);
  float hreg[2][4] = {};
  u16 gpre[3][2][4];
  #pragma unroll
  for (int r = 0; r < 4; r++){
    size_t row = (size_t)(bb + q*4 + r)*384;
    #pragma unroll
    for (int nt = 0; nt < 2; nt++){
      int jj = w*32 + nt*16 + lr;
      #pragma unroll
      for (int g2 = 0; g2 < 3; g2++)
        gpre[g2][nt][r] = gi[row + g2*128 + jj];
    }
  }
  __syncthreads();
  for (int t = 0; t < TT; t++){
    float gif[3][2][4];
    #pragma unroll
    for (int g2 = 0; g2 < 3; g2++)
      #pragma unroll
      for (int nt = 0; nt < 2; nt++)
        #pragma unroll
        for (int r = 0; r < 4; r++)
          gif[g2][nt][r] = b2f(gpre[g2][nt][r]);
    f32x4 acc[3][2] = {};
    if (t > 0){
      #pragma unroll
      for (int kb = 0; kb < 4; kb++){
        bf16x8 a = *(const bf16x8*)(hlds + lr*136 + kb*32 + q*8);
        #pragma unroll
        for (int g2 = 0; g2 < 3; g2++)
          #pragma unroll
          for (int nt = 0; nt < 2; nt++)
            acc[g2][nt] = __builtin_amdgcn_mfma_f32_16x16x32_bf16(a, wreg[g2][nt][kb], acc[g2][nt], 0,0,0);
      }
    }
    __syncthreads();
    #pragma unroll
    for (int nt = 0; nt < 2; nt++)
      #pragma unroll
      for (int r = 0; r < 4; r++){
        int jj = w*32 + nt*16 + lr;
        int b = bb + q*4 + r;
        float rr = sigm(gif[0][nt][r] + acc[0][nt][r] + bh[0][nt]);
        float zz = sigm(gif[1][nt][r] + acc[1][nt][r] + bh[1][nt]);
        float nn = tanh_f(gif[2][nt][r] + rr*(acc[2][nt][r] + bh[2][nt]));
        float hnew = (1.f - zz)*nn + zz*hreg[nt][r];
        hreg[nt][r] = hnew;
        u16 hb = f2b(hnew);
        hlds[(q*4 + r)*136 + jj] = hb;
        seq[(size_t)(t*BSZ + b)*128 + jj] = hb;
      }
    if (t + 1 < TT){
      #pragma unroll
      for (int r = 0; r < 4; r++){
        size_t row = (size_t)((t+1)*BSZ + bb + q*4 + r)*384;
        #pragma unroll
        for (int nt = 0; nt < 2; nt++){
          int jj = w*32 + nt*16 + lr;
          #pragma unroll
          for (int g2 = 0; g2 < 3; g2++)
            gpre[g2][nt][r] = gi[row + g2*128 + jj];
        }
      }
    }
    __syncthreads();
  }
}

extern "C" void kernel_launch(void* const* d_in, const int* in_sizes, int n_in,
                              void* d_out, int out_size, void* d_ws, size_t ws_size,
                              hipStream_t stream)
{
  const void* x    = d_in[0];
  const int* ei    = (const int*)d_in[1];

  const size_t NEED = (size_t)164 << 20;
  if (ws_size < NEED) return;
  char* wsb = (char*)d_ws;
  const size_t KB = 1024, MB = 1024*1024;

  int* syncv = (int*)wsb;                       // 16 KB: 2 layers x 4x512 counters
  int* flag  = (int*)(wsb + 24*KB);
  u16* gw1_c  = (u16*)(wsb + 1*MB + 0);
  u16* gb1_c  = (u16*)(wsb + 1*MB + 64);
  u16* gw2_c  = (u16*)(wsb + 1*MB + 128);
  u16* gb2_c  = (u16*)(wsb + 1*MB + 192);
  u16* gcw_c  = (u16*)(wsb + 1*MB + 256);
  u16* gcb_c  = (u16*)(wsb + 1*MB + 320);
  u16* efb_c  = (u16*)(wsb + 1*MB + 4*KB);
  u16* ebih_c = (u16*)(wsb + 1*MB + 8*KB);
  u16* ebhh_c = (u16*)(wsb + 1*MB + 24*KB);
  u16* dfb_c  = (u16*)(wsb + 1*MB + 40*KB);
  u16* dbih_c = (u16*)(wsb + 1*MB + 45*KB);
  u16* dbhh_c = (u16*)(wsb + 1*MB + 47*KB);
  u16* dlb_c  = (u16*)(wsb + 1*MB + 49*KB);
  u16* wT3    = (u16*)(wsb + 1*MB + 64*KB);
  u16* dlw_c  = (u16*)(wsb + 1*MB + 128*KB);
  u16* efw_c  = (u16*)(wsb + 1*MB + 192*KB);
  u16* wT1    = (u16*)(wsb + 1*MB + 448*KB);
  u16* dfw_c  = (u16*)(wsb + 2*MB);
  u16* wT2    = (u16*)(wsb + 4*MB);
  u16* dwih0_c= (u16*)(wsb + 6*MB);
  u16* dwih1_c= (u16*)(wsb + 7*MB);
  u16* dwhh_c = (u16*)(wsb + 7*MB + 128*KB);
  u16* ewih_c = (u16*)(wsb + 8*MB);
  u16* ewhh_c = (u16*)(wsb + 20*MB);
  u16* res    = (u16*)(wsb + 32*MB);            // 4MB  [GG,128]  GCN out -> seq3
  u16* bufA   = (u16*)(wsb + 36*MB);            // 32MB x0/seq1/seq2/seq4
  u16* bufC   = (u16*)(wsb + 68*MB);            // 96MB gi_enc; later d0
  u16* x_c    = bufC;                           // 4MB alias (dead before gi)
  u16* giD    = (u16*)(wsb + 100*MB);           // 12MB decoder gi (in bufC tail)

  hipMemsetAsync(syncv, 0, 16*KB, stream);
  detect_dtype<<<1, 256, 0, stream>>>(x, flag);

  auto cvt = [&](int idx, u16* dst, int n){
    cvt_bf16<<<(n + 255)/256, 256, 0, stream>>>(d_in[idx], dst, n, flag);
  };
  cvt(0,  x_c,     GG*NNODE*2);
  cvt(2,  gw1_c, 8);  cvt(3, gb1_c, 4);  cvt(4, gw2_c, 8);
  cvt(5,  gb2_c, 2);  cvt(6, gcw_c, 4);  cvt(7, gcb_c, 2);
  cvt(8,  efw_c,   128*1024);   cvt(9,  efb_c, 1024);
  cvt(10, ewih_c,  2*3072*1024);
  cvt(11, ewhh_c,  2*3072*1024);
  cvt(12, ebih_c,  2*3072);     cvt(13, ebhh_c, 2*3072);
  cvt(14, dfw_c,   1024*1024);  cvt(15, dfb_c, 1024);
  cvt(16, dwih0_c, 384*1024);   cvt(17, dwih1_c, 384*128);
  cvt(18, dwhh_c,  2*384*128);
  cvt(19, dbih_c,  2*384);      cvt(20, dbhh_c, 2*384);
  cvt(21, dlw_c,   128*128);    cvt(22, dlb_c, 128);

  transpose_bf16<<<dim3(1024/32, 128/32),  dim3(32,8), 0, stream>>>(efw_c, wT1, 128, 1024);
  transpose_bf16<<<dim3(1024/32, 1024/32), dim3(32,8), 0, stream>>>(dfw_c, wT2, 1024, 1024);
  transpose_bf16<<<dim3(128/32, 128/32),   dim3(32,8), 0, stream>>>(dlw_c, wT3, 128, 128);

  // GCN -> res [GG,128] (b-major)
  gcn_kernel<<<GG, 64, 0, stream>>>(x_c, ei, gw1_c, gb1_c, gw2_c, gb2_c, gcw_c, gcb_c, res);

  // encoder fl: x0 = relu(res @ efw + efb) -> bufA [t][b]
  gemm_nt<<<dim3(1024/128, GG/128), 256, 0, stream>>>(res, wT1, efb_c, bufA, GG, 1024, 128, 1, 0, 1, nullptr);
  // enc layer 0: gi0 -> bufC [t][b]; recurrence -> bufA (seq1)
  gemm_nt<<<dim3(3072/128, GG/128), 256, 0, stream>>>(bufA, ewih_c, ebih_c, bufC, GG, 3072, 1024, 0, 1, 1, nullptr);
  enc_rec2<<<NWG2, 256, 0, stream>>>(bufC, ewhh_c, ebhh_c, bufA, syncv);
  // enc layer 1: gi1 -> bufC [t][b]; recurrence -> bufA (seq2)
  gemm_nt<<<dim3(3072/128, GG/128), 256, 0, stream>>>(bufA, ewih_c + 3072*1024, ebih_c + 3072, bufC, GG, 3072, 1024, 0, 1, 1, nullptr);
  enc_rec2<<<NWG2, 256, 0, stream>>>(bufC, ewhh_c + 3072*1024, ebhh_c + 3072, bufA, syncv + 4*TT);

  // decoder fl: d0 = relu(seq2 @ dfw + dfb) -> bufC prefix [t][b]
  u16* d0 = bufC;
  gemm_nt<<<dim3(1024/128, GG/128), 256, 0, stream>>>(bufA, wT2, dfb_c, d0, GG, 1024, 1024, 1, 1, 1, nullptr);
  // dec layer 0: gi -> giD [t][b]; recurrence -> res (seq3, [t][b])
  gemm_nt<<<dim3(384/128, GG/128), 256, 0, stream>>>(d0, dwih0_c, dbih_c, giD, GG, 384, 1024, 0, 1, 1, nullptr);
  dec_rec<<<2, 256, 0, stream>>>(giD, dwhh_c, dbhh_c, res);
  // dec layer 1: gi -> giD [t][b]; recurrence -> bufA (seq4, [t][b])
  gemm_nt<<<dim3(384/128, GG/128), 256, 0, stream>>>(res, dwih1_c, dbih_c + 384, giD, GG, 384, 128, 0, 1, 1, nullptr);
  dec_rec<<<2, 256, 0, stream>>>(giD, dwhh_c + 384*128, dbhh_c + 384, bufA);

  // final linear: A = seq4 [t][b] -> d_out rows b*TT+t (bf16 or f32 per dtype)
  gemm_nt<<<dim3(128/128, GG/128), 256, 0, stream>>>(bufA, wT3, dlb_c, d_out, GG, 128, 128, 0, 1, 0, flag);
}

// Round 7
// 11717.551 us; speedup vs baseline: 1.6540x; 1.6540x over previous
//
#include <hip/hip_runtime.h>

typedef unsigned short u16;
typedef unsigned long long u64;
typedef __attribute__((ext_vector_type(8))) short bf16x8;
typedef __attribute__((ext_vector_type(4))) float f32x4;

#define BSZ 32
#define TT 512
#define GG (BSZ*TT)      // 16384
#define NNODE 64
#define EE 126
#define H8 1024
#define H3 3072

__device__ __forceinline__ float b2f(u16 u){
  union { unsigned i; float f; } v; v.i = ((unsigned)u) << 16; return v.f;
}
__device__ __forceinline__ u16 f2b(float f){
  unsigned i = __float_as_uint(f);
  unsigned r = (i + 0x7FFFu + ((i >> 16) & 1u)) >> 16;   // RNE
  return (u16)r;
}
__device__ __forceinline__ float sigm(float x){ return 1.f/(1.f+__expf(-x)); }
__device__ __forceinline__ float tanh_f(float x){
  float xc = fminf(fmaxf(x, -15.f), 15.f);
  float e = __expf(2.f*xc);
  return (e-1.f)/(e+1.f);
}
__device__ __forceinline__ int prow(int m, int perm){
  return perm ? ((m & (TT-1))*BSZ + (m >> 9)) : m;
}
__device__ __forceinline__ u64 aload64(const u64* p){
  return __hip_atomic_load(p, __ATOMIC_RELAXED, __HIP_MEMORY_SCOPE_AGENT);
}
// wait until the 8 split counters for round t sum to 128
__device__ __forceinline__ void spin128(int* base, int t){
  for (;;){
    int s = 0;
    #pragma unroll
    for (int i = 0; i < 8; i++)
      s += __hip_atomic_load(&base[i*TT + t], __ATOMIC_RELAXED, __HIP_MEMORY_SCOPE_AGENT);
    if (s == 128) break;
    __builtin_amdgcn_s_sleep(1);
  }
  asm volatile("" ::: "memory");
}

// ---------------- dtype detection: *flag = 1 if inputs are fp32 ----------------
__global__ __launch_bounds__(256) void detect_dtype(const void* xraw, int* flag){
  __shared__ int cnt;
  if (threadIdx.x == 0) cnt = 0;
  __syncthreads();
  const u16* p = (const u16*)xraw;
  u16 u = p[2*threadIdx.x];
  int e = (u >> 7) & 0xFF;
  int weird = (e < 100 || e > 134) ? 1 : 0;
  atomicAdd(&cnt, weird);
  __syncthreads();
  if (threadIdx.x == 0) *flag = (cnt > 128) ? 1 : 0;
}

__global__ __launch_bounds__(256) void cvt_bf16(const void* __restrict__ in,
                                                u16* __restrict__ out, int n,
                                                const int* __restrict__ flag){
  int i = blockIdx.x*256 + threadIdx.x;
  if (i >= n) return;
  if (*flag) out[i] = f2b(((const float*)in)[i]);
  else       out[i] = ((const u16*)in)[i];
}

// ---------------- GCN ----------------
__global__ __launch_bounds__(64) void gcn_kernel(
    const u16* __restrict__ x, const int* __restrict__ ei,
    const u16* __restrict__ w1, const u16* __restrict__ b1,
    const u16* __restrict__ w2, const u16* __restrict__ b2,
    const u16* __restrict__ cw, const u16* __restrict__ cb,
    u16* __restrict__ res)
{
  __shared__ int se[EE], de[EE];
  __shared__ float dinv[NNODE];
  __shared__ float nrm[EE];
  __shared__ float hs[NNODE][4];
  const int n = threadIdx.x;
  const int g = blockIdx.x;
  for (int e = n; e < EE; e += 64){ se[e] = ei[e]; de[e] = ei[EE + e]; }
  __syncthreads();
  int cnt = 0;
  for (int e = 0; e < EE; e++) cnt += (de[e] == n) ? 1 : 0;
  float di = rsqrtf(1.0f + (float)cnt);
  dinv[n] = di;
  float x0 = b2f(x[((size_t)g*NNODE + n)*2 + 0]);
  float x1 = b2f(x[((size_t)g*NNODE + n)*2 + 1]);
  float hw[4];
  #pragma unroll
  for (int c = 0; c < 4; c++) hw[c] = x0*b2f(w1[c]) + x1*b2f(w1[4+c]);
  #pragma unroll
  for (int c = 0; c < 4; c++) hs[n][c] = hw[c];
  __syncthreads();
  for (int e = n; e < EE; e += 64) nrm[e] = dinv[se[e]] * dinv[de[e]];
  __syncthreads();
  float selfc = di*di;
  float agg[4];
  #pragma unroll
  for (int c = 0; c < 4; c++) agg[c] = hw[c]*selfc;
  for (int e = 0; e < EE; e++){
    if (de[e] == n){
      float w = nrm[e]; int s = se[e];
      #pragma unroll
      for (int c = 0; c < 4; c++) agg[c] += hs[s][c]*w;
    }
  }
  float h1[4];
  #pragma unroll
  for (int c = 0; c < 4; c++) h1[c] = tanh_f(agg[c] + b2f(b1[c]));
  __syncthreads();
  float hw2[2];
  #pragma unroll
  for (int c = 0; c < 2; c++){
    float s = 0.f;
    #pragma unroll
    for (int k = 0; k < 4; k++) s += h1[k]*b2f(w2[k*2+c]);
    hw2[c] = s;
    hs[n][c] = s;
  }
  __syncthreads();
  float agg2[2] = { hw2[0]*selfc, hw2[1]*selfc };
  for (int e = 0; e < EE; e++){
    if (de[e] == n){
      float w = nrm[e]; int s = se[e];
      agg2[0] += hs[s][0]*w;
      agg2[1] += hs[s][1]*w;
    }
  }
  float h2a = tanh_f(agg2[0] + b2f(b2[0]));
  float h2b = tanh_f(agg2[1] + b2f(b2[1]));
  #pragma unroll
  for (int c = 0; c < 2; c++){
    float o = h2a*b2f(cw[c]) + h2b*b2f(cw[2+c]) + b2f(cb[c]);
    res[(size_t)g*128 + n*2 + c] = f2b(o);
  }
}

// ---------------- bf16 transpose ----------------
__global__ __launch_bounds__(256) void transpose_bf16(
    const u16* __restrict__ in, u16* __restrict__ out, int R, int C)
{
  __shared__ u16 tile[32][33];
  int c0 = blockIdx.x*32, r0 = blockIdx.y*32;
  for (int i = threadIdx.y; i < 32; i += 8)
    tile[i][threadIdx.x] = in[(size_t)(r0+i)*C + c0 + threadIdx.x];
  __syncthreads();
  for (int i = threadIdx.y; i < 32; i += 8)
    out[(size_t)(c0+i)*R + r0 + threadIdx.x] = tile[threadIdx.x][i];
}

// ---------------- GEMM NT ----------------
__global__ __launch_bounds__(256) void gemm_nt(
    const u16* __restrict__ A, const u16* __restrict__ Bm,
    const u16* __restrict__ bias, void* __restrict__ C,
    int M, int N, int K, int relu, int permA, int permC,
    const int* __restrict__ outflag)
{
  const int wave = threadIdx.x >> 6;
  const int lane = threadIdx.x & 63;
  const int wm = wave >> 1, wn = wave & 1;
  const int q = lane >> 4, lr = lane & 15;
  const int mBase = blockIdx.y*128 + wm*64;
  const int nBase = blockIdx.x*128 + wn*64;
  f32x4 acc[4][4] = {};
  const u16* ap[4]; const u16* bp[4];
  #pragma unroll
  for (int i = 0; i < 4; i++){
    ap[i] = A + (size_t)prow(mBase + i*16 + lr, permA)*K + q*8;
    bp[i] = Bm + (size_t)(nBase + i*16 + lr)*K + q*8;
  }
  for (int kb = 0; kb < K; kb += 32){
    bf16x8 av[4], bv[4];
    #pragma unroll
    for (int i = 0; i < 4; i++){
      av[i] = *(const bf16x8*)ap[i]; bv[i] = *(const bf16x8*)bp[i];
      ap[i] += 32; bp[i] += 32;
    }
    #pragma unroll
    for (int mi = 0; mi < 4; mi++)
      #pragma unroll
      for (int ni = 0; ni < 4; ni++)
        acc[mi][ni] = __builtin_amdgcn_mfma_f32_16x16x32_bf16(av[mi], bv[ni], acc[mi][ni], 0, 0, 0);
  }
  const int of32 = outflag ? *outflag : 0;
  #pragma unroll
  for (int ni = 0; ni < 4; ni++){
    int col = nBase + ni*16 + lr;
    float bb = bias ? b2f(bias[col]) : 0.f;
    #pragma unroll
    for (int mi = 0; mi < 4; mi++){
      #pragma unroll
      for (int r = 0; r < 4; r++){
        int row = prow(mBase + mi*16 + q*4 + r, permC);
        float v = acc[mi][ni][r] + bb;
        if (relu) v = fmaxf(v, 0.f);
        size_t idx = (size_t)row*N + col;
        if (of32) ((float*)C)[idx] = v;
        else      ((u16*)C)[idx]   = f2b(v);
      }
    }
  }
}

// ---------------- pipelined 2-layer encoder recurrence ----------------
// 256 WGs x 64 thr (1 wave each). wids 0-127 = layer 0 (exact round-4
// structure, 9.34 us/step proven); wids 128-255 = layer 1, computing its
// gi on the fly from h0[t] (kills the gi1 GEMM + 192 MB traffic).
// DECOUPLED counters: L0 never waits on L1 -> free-runs; L1 waits on
// L0cnt[t] (monotone, usually already satisfied) + L1cnt[t-1].
// XCD-paired mapping (jg = wid&63, half = wid>>6): the two batch-half
// waves of a column group land on bids 64 apart -> same XCD under %8
// round-robin -> per-XCD weight footprint = 18MB/8 = 2.25MB (L2-resident;
// round-5's adjacent-bid mapping duplicated slices -> 4.5MB -> thrash).
// h1seq aliases gi's dead prefix: h1[t] spans [64K*t,64K*(t+1)) <
// gi0[t] start 192K*t for t>=1; t=0 region consumed before L1 writes
// (guaranteed by full L0[t] barrier). All h traffic = relaxed agent-scope
// atomics (L2-bypass, L3-coherent).
__global__ __launch_bounds__(64) void enc_pipe(
    const u16* __restrict__ gi,    // [TT*32,3072] t-major (bih0 incl)
    const u16* __restrict__ wih1,  // [3072,1024]
    const u16* __restrict__ whh0,  // [3072,1024]
    const u16* __restrict__ whh1,  // [3072,1024]
    const u16* __restrict__ bih1, const u16* __restrict__ bhh0,
    const u16* __restrict__ bhh1,
    u16* __restrict__ h0seq,       // [TT*32,1024] t-major
    u16* __restrict__ h1seq,       // [TT*32,1024] t-major (gi dead prefix)
    int* __restrict__ cnt)         // [16*TT]: L0 = [0,8*TT), L1 = [8*TT,16*TT)
{
  const int wid = blockIdx.x;
  const int lane = threadIdx.x & 63;
  const int q = lane >> 4, lr = lane & 15;
  const int sub = wid & 7;
  float hreg[4] = {0.f,0.f,0.f,0.f};
  int* c0 = cnt;
  int* c1 = cnt + 8*TT;

  if (wid < 128){
    // ---------- layer 0 (round-4 structure) ----------
    const int jg = wid & 63, half = wid >> 6;
    const int j = jg*16 + lr, bbase = half*16;
    const float bh_r = b2f(bhh0[j]);
    const float bh_z = b2f(bhh0[H8 + j]);
    const float bh_n = b2f(bhh0[2*H8 + j]);
    const u16* wp0 = whh0 + (size_t)(0*H8 + j)*H8 + q*8;
    const u16* wp1 = whh0 + (size_t)(1*H8 + j)*H8 + q*8;
    const u16* wp2 = whh0 + (size_t)(2*H8 + j)*H8 + q*8;
    u16 gpre[12];
    #pragma unroll
    for (int r = 0; r < 4; r++){
      size_t row = (size_t)(bbase + q*4 + r)*H3;
      gpre[r]   = gi[row + j];
      gpre[4+r] = gi[row + H8 + j];
      gpre[8+r] = gi[row + 2*H8 + j];
    }
    for (int t = 0; t < TT; t++){
      if (t > 0) spin128(c0, t - 1);
      float gr_[4], gz_[4], gn_[4];
      #pragma unroll
      for (int r = 0; r < 4; r++){
        gr_[r] = b2f(gpre[r]); gz_[r] = b2f(gpre[4+r]); gn_[r] = b2f(gpre[8+r]);
      }
      f32x4 acc0 = {}, acc1 = {}, acc2 = {};
      if (t > 0){
        const u16* ap = h0seq + (size_t)((t-1)*BSZ + bbase + lr)*H8 + q*8;
        #pragma unroll 8
        for (int kb = 0; kb < 32; kb++){
          const u64* p = (const u64*)(ap + kb*32);
          union { u64 v[2]; bf16x8 b; } A; A.v[0] = aload64(p); A.v[1] = aload64(p+1);
          bf16x8 w0 = *(const bf16x8*)(wp0 + kb*32);
          bf16x8 w1 = *(const bf16x8*)(wp1 + kb*32);
          bf16x8 w2 = *(const bf16x8*)(wp2 + kb*32);
          acc0 = __builtin_amdgcn_mfma_f32_16x16x32_bf16(A.b, w0, acc0, 0,0,0);
          acc1 = __builtin_amdgcn_mfma_f32_16x16x32_bf16(A.b, w1, acc1, 0,0,0);
          acc2 = __builtin_amdgcn_mfma_f32_16x16x32_bf16(A.b, w2, acc2, 0,0,0);
        }
      }
      #pragma unroll
      for (int r = 0; r < 4; r++){
        float rr = sigm(gr_[r] + acc0[r] + bh_r);
        float zz = sigm(gz_[r] + acc1[r] + bh_z);
        float nn = tanh_f(gn_[r] + rr*(acc2[r] + bh_n));
        float hnew = (1.f - zz)*nn + zz*hreg[r];
        hreg[r] = hnew;
        __hip_atomic_store(&h0seq[(size_t)(t*BSZ + bbase + q*4 + r)*H8 + j], f2b(hnew),
                           __ATOMIC_RELAXED, __HIP_MEMORY_SCOPE_AGENT);
      }
      asm volatile("s_waitcnt vmcnt(0)" ::: "memory");
      if (lane == 0)
        __hip_atomic_fetch_add(&c0[sub*TT + t], 1, __ATOMIC_RELAXED, __HIP_MEMORY_SCOPE_AGENT);
      if (t + 1 < TT){
        #pragma unroll
        for (int r = 0; r < 4; r++){
          size_t row = (size_t)((t+1)*BSZ + bbase + q*4 + r)*H3;
          gpre[r]   = gi[row + j];
          gpre[4+r] = gi[row + H8 + j];
          gpre[8+r] = gi[row + 2*H8 + j];
        }
      }
    }
  } else {
    // ---------- layer 1 (gi computed on the fly) ----------
    const int wid2 = wid - 128;
    const int jg = wid2 & 63, half = wid2 >> 6;
    const int j = jg*16 + lr, bbase = half*16;
    const float bir = b2f(bih1[j]);
    const float biz = b2f(bih1[H8 + j]);
    const float bin = b2f(bih1[2*H8 + j]);
    const float bhr = b2f(bhh1[j]);
    const float bhz = b2f(bhh1[H8 + j]);
    const float bhn = b2f(bhh1[2*H8 + j]);
    const u16* ip0 = wih1 + (size_t)(0*H8 + j)*H8 + q*8;
    const u16* ip1 = wih1 + (size_t)(1*H8 + j)*H8 + q*8;
    const u16* ip2 = wih1 + (size_t)(2*H8 + j)*H8 + q*8;
    const u16* hp0 = whh1 + (size_t)(0*H8 + j)*H8 + q*8;
    const u16* hp1 = whh1 + (size_t)(1*H8 + j)*H8 + q*8;
    const u16* hp2 = whh1 + (size_t)(2*H8 + j)*H8 + q*8;
    for (int t = 0; t < TT; t++){
      spin128(c0, t);                 // h0[t] ready (usually already true)
      if (t > 0) spin128(c1, t - 1);  // h1[t-1] ready
      f32x4 aI0 = {}, aI1 = {}, aI2 = {}, aH0 = {}, aH1 = {}, aH2 = {};
      const u16* a0p = h0seq + (size_t)(t*BSZ + bbase + lr)*H8 + q*8;
      if (t > 0){
        const u16* a1p = h1seq + (size_t)((t-1)*BSZ + bbase + lr)*H8 + q*8;
        #pragma unroll 4
        for (int kb = 0; kb < 32; kb++){
          const u64* p0 = (const u64*)(a0p + kb*32);
          union { u64 v[2]; bf16x8 b; } A0; A0.v[0] = aload64(p0); A0.v[1] = aload64(p0+1);
          const u64* p1 = (const u64*)(a1p + kb*32);
          union { u64 v[2]; bf16x8 b; } A1; A1.v[0] = aload64(p1); A1.v[1] = aload64(p1+1);
          bf16x8 i0 = *(const bf16x8*)(ip0 + kb*32);
          bf16x8 i1 = *(const bf16x8*)(ip1 + kb*32);
          bf16x8 i2 = *(const bf16x8*)(ip2 + kb*32);
          bf16x8 h0v = *(const bf16x8*)(hp0 + kb*32);
          bf16x8 h1v = *(const bf16x8*)(hp1 + kb*32);
          bf16x8 h2v = *(const bf16x8*)(hp2 + kb*32);
          aI0 = __builtin_amdgcn_mfma_f32_16x16x32_bf16(A0.b, i0, aI0, 0,0,0);
          aI1 = __builtin_amdgcn_mfma_f32_16x16x32_bf16(A0.b, i1, aI1, 0,0,0);
          aI2 = __builtin_amdgcn_mfma_f32_16x16x32_bf16(A0.b, i2, aI2, 0,0,0);
          aH0 = __builtin_amdgcn_mfma_f32_16x16x32_bf16(A1.b, h0v, aH0, 0,0,0);
          aH1 = __builtin_amdgcn_mfma_f32_16x16x32_bf16(A1.b, h1v, aH1, 0,0,0);
          aH2 = __builtin_amdgcn_mfma_f32_16x16x32_bf16(A1.b, h2v, aH2, 0,0,0);
        }
      } else {
        #pragma unroll 8
        for (int kb = 0; kb < 32; kb++){
          const u64* p0 = (const u64*)(a0p + kb*32);
          union { u64 v[2]; bf16x8 b; } A0; A0.v[0] = aload64(p0); A0.v[1] = aload64(p0+1);
          bf16x8 i0 = *(const bf16x8*)(ip0 + kb*32);
          bf16x8 i1 = *(const bf16x8*)(ip1 + kb*32);
          bf16x8 i2 = *(const bf16x8*)(ip2 + kb*32);
          aI0 = __builtin_amdgcn_mfma_f32_16x16x32_bf16(A0.b, i0, aI0, 0,0,0);
          aI1 = __builtin_amdgcn_mfma_f32_16x16x32_bf16(A0.b, i1, aI1, 0,0,0);
          aI2 = __builtin_amdgcn_mfma_f32_16x16x32_bf16(A0.b, i2, aI2, 0,0,0);
        }
      }
      #pragma unroll
      for (int r = 0; r < 4; r++){
        float rr = sigm(aI0[r] + bir + aH0[r] + bhr);
        float zz = sigm(aI1[r] + biz + aH1[r] + bhz);
        float nn = tanh_f(aI2[r] + bin + rr*(aH2[r] + bhn));
        float hnew = (1.f - zz)*nn + zz*hreg[r];
        hreg[r] = hnew;
        __hip_atomic_store(&h1seq[(size_t)(t*BSZ + bbase + q*4 + r)*H8 + j], f2b(hnew),
                           __ATOMIC_RELAXED, __HIP_MEMORY_SCOPE_AGENT);
      }
      asm volatile("s_waitcnt vmcnt(0)" ::: "memory");
      if (lane == 0)
        __hip_atomic_fetch_add(&c1[sub*TT + t], 1, __ATOMIC_RELAXED, __HIP_MEMORY_SCOPE_AGENT);
    }
  }
}

// ---------------- decoder GRU recurrence (H=128), round-4 proven ----------------
__global__ __launch_bounds__(256) void dec_rec(
    const u16* __restrict__ gi,   // [TT*32, 384] t-major (bih included)
    const u16* __restrict__ whh,  // [384, 128]
    const u16* __restrict__ bhh,  // [384]
    u16* __restrict__ seq)        // out [TT*32, 128] t-major
{
  __shared__ u16 hlds[16*136];
  const int bb = blockIdx.x*16;
  const int tid = threadIdx.x;
  const int w = tid >> 6, lane = tid & 63, q = lane >> 4, lr = lane & 15;
  bf16x8 wreg[3][2][4];
  #pragma unroll
  for (int g2 = 0; g2 < 3; g2++)
    #pragma unroll
    for (int nt = 0; nt < 2; nt++){
      int jj = g2*128 + w*32 + nt*16 + lr;
      #pragma unroll
      for (int kb = 0; kb < 4; kb++)
        wreg[g2][nt][kb] = *(const bf16x8*)(whh + (size_t)jj*128 + kb*32 + q*8);
    }
  float bh[3][2];
  #pragma unroll
  for (int g2 = 0; g2 < 3; g2++)
    #pragma unroll
    for (int nt = 0; nt < 2; nt++)
      bh[g2][nt] = b2f(bhh[g2*128 + w*32 + nt*16 + lr]);
  float hreg[2][4] = {};
  u16 gpre[3][2][4];
  #pragma unroll
  for (int r = 0; r < 4; r++){
    size_t row = (size_t)(bb + q*4 + r)*384;
    #pragma unroll
    for (int nt = 0; nt < 2; nt++){
      int jj = w*32 + nt*16 + lr;
      #pragma unroll
      for (int g2 = 0; g2 < 3; g2++)
        gpre[g2][nt][r] = gi[row + g2*128 + jj];
    }
  }
  __syncthreads();
  for (int t = 0; t < TT; t++){
    float gif[3][2][4];
    #pragma unroll
    for (int g2 = 0; g2 < 3; g2++)
      #pragma unroll
      for (int nt = 0; nt < 2; nt++)
        #pragma unroll
        for (int r = 0; r < 4; r++)
          gif[g2][nt][r] = b2f(gpre[g2][nt][r]);
    f32x4 acc[3][2] = {};
    if (t > 0){
      #pragma unroll
      for (int kb = 0; kb < 4; kb++){
        bf16x8 a = *(const bf16x8*)(hlds + lr*136 + kb*32 + q*8);
        #pragma unroll
        for (int g2 = 0; g2 < 3; g2++)
          #pragma unroll
          for (int nt = 0; nt < 2; nt++)
            acc[g2][nt] = __builtin_amdgcn_mfma_f32_16x16x32_bf16(a, wreg[g2][nt][kb], acc[g2][nt], 0,0,0);
      }
    }
    __syncthreads();
    #pragma unroll
    for (int nt = 0; nt < 2; nt++)
      #pragma unroll
      for (int r = 0; r < 4; r++){
        int jj = w*32 + nt*16 + lr;
        int b = bb + q*4 + r;
        float rr = sigm(gif[0][nt][r] + acc[0][nt][r] + bh[0][nt]);
        float zz = sigm(gif[1][nt][r] + acc[1][nt][r] + bh[1][nt]);
        float nn = tanh_f(gif[2][nt][r] + rr*(acc[2][nt][r] + bh[2][nt]));
        float hnew = (1.f - zz)*nn + zz*hreg[nt][r];
        hreg[nt][r] = hnew;
        u16 hb = f2b(hnew);
        hlds[(q*4 + r)*136 + jj] = hb;
        seq[(size_t)(t*BSZ + b)*128 + jj] = hb;
      }
    if (t + 1 < TT){
      #pragma unroll
      for (int r = 0; r < 4; r++){
        size_t row = (size_t)((t+1)*BSZ + bb + q*4 + r)*384;
        #pragma unroll
        for (int nt = 0; nt < 2; nt++){
          int jj = w*32 + nt*16 + lr;
          #pragma unroll
          for (int g2 = 0; g2 < 3; g2++)
            gpre[g2][nt][r] = gi[row + g2*128 + jj];
        }
      }
    }
    __syncthreads();
  }
}

extern "C" void kernel_launch(void* const* d_in, const int* in_sizes, int n_in,
                              void* d_out, int out_size, void* d_ws, size_t ws_size,
                              hipStream_t stream)
{
  const void* x    = d_in[0];
  const int* ei    = (const int*)d_in[1];

  const size_t NEED = (size_t)164 << 20;
  if (ws_size < NEED) return;
  char* wsb = (char*)d_ws;
  const size_t KB = 1024, MB = 1024*1024;

  int* syncv = (int*)wsb;                       // 32 KB: 16x512 counters
  int* flag  = (int*)(wsb + 40*KB);
  u16* gw1_c  = (u16*)(wsb + 1*MB + 0);
  u16* gb1_c  = (u16*)(wsb + 1*MB + 64);
  u16* gw2_c  = (u16*)(wsb + 1*MB + 128);
  u16* gb2_c  = (u16*)(wsb + 1*MB + 192);
  u16* gcw_c  = (u16*)(wsb + 1*MB + 256);
  u16* gcb_c  = (u16*)(wsb + 1*MB + 320);
  u16* efb_c  = (u16*)(wsb + 1*MB + 4*KB);
  u16* ebih_c = (u16*)(wsb + 1*MB + 8*KB);
  u16* ebhh_c = (u16*)(wsb + 1*MB + 24*KB);
  u16* dfb_c  = (u16*)(wsb + 1*MB + 40*KB);
  u16* dbih_c = (u16*)(wsb + 1*MB + 45*KB);
  u16* dbhh_c = (u16*)(wsb + 1*MB + 47*KB);
  u16* dlb_c  = (u16*)(wsb + 1*MB + 49*KB);
  u16* wT3    = (u16*)(wsb + 1*MB + 64*KB);
  u16* dlw_c  = (u16*)(wsb + 1*MB + 128*KB);
  u16* efw_c  = (u16*)(wsb + 1*MB + 192*KB);
  u16* wT1    = (u16*)(wsb + 1*MB + 448*KB);
  u16* dfw_c  = (u16*)(wsb + 2*MB);
  u16* wT2    = (u16*)(wsb + 4*MB);
  u16* dwih0_c= (u16*)(wsb + 6*MB);
  u16* dwih1_c= (u16*)(wsb + 7*MB);
  u16* dwhh_c = (u16*)(wsb + 7*MB + 128*KB);
  u16* ewih_c = (u16*)(wsb + 8*MB);             // 12MB [2,3072,1024]
  u16* ewhh_c = (u16*)(wsb + 20*MB);            // 12MB
  u16* res    = (u16*)(wsb + 32*MB);            // 4MB  GCN out -> seq3
  u16* bufA   = (u16*)(wsb + 36*MB);            // 32MB x0 -> h0seq -> seq4
  u16* bufC   = (u16*)(wsb + 68*MB);            // 96MB gi0; h1seq prefix; d0; giD
  u16* x_c    = bufC;                           // 4MB alias (dead before gi0)
  u16* h1seq  = bufC;                           // [TT*32,1024] in gi0 dead prefix
  u16* d0     = (u16*)(wsb + 102*MB);           // 32MB (inside bufC, after h1seq)
  u16* giD    = (u16*)(wsb + 136*MB);           // 12MB (inside bufC tail)

  hipMemsetAsync(syncv, 0, 32*KB, stream);
  detect_dtype<<<1, 256, 0, stream>>>(x, flag);

  auto cvt = [&](int idx, u16* dst, int n){
    cvt_bf16<<<(n + 255)/256, 256, 0, stream>>>(d_in[idx], dst, n, flag);
  };
  cvt(0,  x_c,     GG*NNODE*2);
  cvt(2,  gw1_c, 8);  cvt(3, gb1_c, 4);  cvt(4, gw2_c, 8);
  cvt(5,  gb2_c, 2);  cvt(6, gcw_c, 4);  cvt(7, gcb_c, 2);
  cvt(8,  efw_c,   128*1024);   cvt(9,  efb_c, 1024);
  cvt(10, ewih_c,  2*3072*1024);
  cvt(11, ewhh_c,  2*3072*1024);
  cvt(12, ebih_c,  2*3072);     cvt(13, ebhh_c, 2*3072);
  cvt(14, dfw_c,   1024*1024);  cvt(15, dfb_c, 1024);
  cvt(16, dwih0_c, 384*1024);   cvt(17, dwih1_c, 384*128);
  cvt(18, dwhh_c,  2*384*128);
  cvt(19, dbih_c,  2*384);      cvt(20, dbhh_c, 2*384);
  cvt(21, dlw_c,   128*128);    cvt(22, dlb_c, 128);

  transpose_bf16<<<dim3(1024/32, 128/32),  dim3(32,8), 0, stream>>>(efw_c, wT1, 128, 1024);
  transpose_bf16<<<dim3(1024/32, 1024/32), dim3(32,8), 0, stream>>>(dfw_c, wT2, 1024, 1024);
  transpose_bf16<<<dim3(128/32, 128/32),   dim3(32,8), 0, stream>>>(dlw_c, wT3, 128, 128);

  // GCN -> res [GG,128] (b-major)
  gcn_kernel<<<GG, 64, 0, stream>>>(x_c, ei, gw1_c, gb1_c, gw2_c, gb2_c, gcw_c, gcb_c, res);

  // encoder fl: x0 = relu(res @ efw + efb) -> bufA [t][b]
  gemm_nt<<<dim3(1024/128, GG/128), 256, 0, stream>>>(res, wT1, efb_c, bufA, GG, 1024, 128, 1, 0, 1, nullptr);
  // enc layer-0 gi: x0 @ ewih0 -> bufC [t][b][3072]
  gemm_nt<<<dim3(3072/128, GG/128), 256, 0, stream>>>(bufA, ewih_c, ebih_c, bufC, GG, 3072, 1024, 0, 1, 1, nullptr);
  // pipelined both-layer recurrence: h0 -> bufA, h1 -> h1seq (gi dead prefix)
  enc_pipe<<<256, 64, 0, stream>>>(bufC, ewih_c + 3072*1024, ewhh_c, ewhh_c + 3072*1024,
                                   ebih_c + 3072, ebhh_c, ebhh_c + 3072,
                                   bufA, h1seq, syncv);

  // decoder fl: d0 = relu(h1seq @ dfw + dfb) -> d0 [t][b]
  gemm_nt<<<dim3(1024/128, GG/128), 256, 0, stream>>>(h1seq, wT2, dfb_c, d0, GG, 1024, 1024, 1, 1, 1, nullptr);
  // dec layer-0 gi: d0 @ dwih0 -> giD [t][b][384]
  gemm_nt<<<dim3(384/128, GG/128), 256, 0, stream>>>(d0, dwih0_c, dbih_c, giD, GG, 384, 1024, 0, 1, 1, nullptr);
  dec_rec<<<2, 256, 0, stream>>>(giD, dwhh_c, dbhh_c, res);
  // dec layer-1 gi: seq3 @ dwih1 -> giD
  gemm_nt<<<dim3(384/128, GG/128), 256, 0, stream>>>(res, dwih1_c, dbih_c + 384, giD, GG, 384, 128, 0, 1, 1, nullptr);
  dec_rec<<<2, 256, 0, stream>>>(giD, dwhh_c + 384*128, dbhh_c + 384, bufA);

  // final linear: seq4 [t][b] -> d_out rows b*TT+t (bf16 or f32 per dtype)
  gemm_nt<<<dim3(128/128, GG/128), 256, 0, stream>>>(bufA, wT3, dlb_c, d_out, GG, 128, 128, 0, 1, 0, flag);
}

// Round 8
// 10826.571 us; speedup vs baseline: 1.7902x; 1.0823x over previous
//
#include <hip/hip_runtime.h>

typedef unsigned short u16;
typedef unsigned long long u64;
typedef __attribute__((ext_vector_type(8))) short bf16x8;
typedef __attribute__((ext_vector_type(4))) float f32x4;

#define BSZ 32
#define TT 512
#define GG (BSZ*TT)      // 16384
#define NNODE 64
#define EE 126
#define H8 1024
#define H3 3072

__device__ __forceinline__ float b2f(u16 u){
  union { unsigned i; float f; } v; v.i = ((unsigned)u) << 16; return v.f;
}
__device__ __forceinline__ u16 f2b(float f){
  unsigned i = __float_as_uint(f);
  unsigned r = (i + 0x7FFFu + ((i >> 16) & 1u)) >> 16;   // RNE
  return (u16)r;
}
__device__ __forceinline__ float sigm(float x){ return 1.f/(1.f+__expf(-x)); }
__device__ __forceinline__ float tanh_f(float x){
  float xc = fminf(fmaxf(x, -15.f), 15.f);
  float e = __expf(2.f*xc);
  return (e-1.f)/(e+1.f);
}
__device__ __forceinline__ int prow(int m, int perm){
  return perm ? ((m & (TT-1))*BSZ + (m >> 9)) : m;
}
__device__ __forceinline__ u64 aload64(const u64* p){
  return __hip_atomic_load(p, __ATOMIC_RELAXED, __HIP_MEMORY_SCOPE_AGENT);
}
// wait until the 8 split counters for round t sum to 128
__device__ __forceinline__ void spin128(int* base, int t){
  for (;;){
    int s = 0;
    #pragma unroll
    for (int i = 0; i < 8; i++)
      s += __hip_atomic_load(&base[i*TT + t], __ATOMIC_RELAXED, __HIP_MEMORY_SCOPE_AGENT);
    if (s == 128) break;
    __builtin_amdgcn_s_sleep(1);
  }
  asm volatile("" ::: "memory");
}

// ---------------- dtype detection: *flag = 1 if inputs are fp32 ----------------
__global__ __launch_bounds__(256) void detect_dtype(const void* xraw, int* flag){
  __shared__ int cnt;
  if (threadIdx.x == 0) cnt = 0;
  __syncthreads();
  const u16* p = (const u16*)xraw;
  u16 u = p[2*threadIdx.x];
  int e = (u >> 7) & 0xFF;
  int weird = (e < 100 || e > 134) ? 1 : 0;
  atomicAdd(&cnt, weird);
  __syncthreads();
  if (threadIdx.x == 0) *flag = (cnt > 128) ? 1 : 0;
}

__global__ __launch_bounds__(256) void cvt_bf16(const void* __restrict__ in,
                                                u16* __restrict__ out, int n,
                                                const int* __restrict__ flag){
  int i = blockIdx.x*256 + threadIdx.x;
  if (i >= n) return;
  if (*flag) out[i] = f2b(((const float*)in)[i]);
  else       out[i] = ((const u16*)in)[i];
}

// ---------------- GCN ----------------
__global__ __launch_bounds__(64) void gcn_kernel(
    const u16* __restrict__ x, const int* __restrict__ ei,
    const u16* __restrict__ w1, const u16* __restrict__ b1,
    const u16* __restrict__ w2, const u16* __restrict__ b2,
    const u16* __restrict__ cw, const u16* __restrict__ cb,
    u16* __restrict__ res)
{
  __shared__ int se[EE], de[EE];
  __shared__ float dinv[NNODE];
  __shared__ float nrm[EE];
  __shared__ float hs[NNODE][4];
  const int n = threadIdx.x;
  const int g = blockIdx.x;
  for (int e = n; e < EE; e += 64){ se[e] = ei[e]; de[e] = ei[EE + e]; }
  __syncthreads();
  int cnt = 0;
  for (int e = 0; e < EE; e++) cnt += (de[e] == n) ? 1 : 0;
  float di = rsqrtf(1.0f + (float)cnt);
  dinv[n] = di;
  float x0 = b2f(x[((size_t)g*NNODE + n)*2 + 0]);
  float x1 = b2f(x[((size_t)g*NNODE + n)*2 + 1]);
  float hw[4];
  #pragma unroll
  for (int c = 0; c < 4; c++) hw[c] = x0*b2f(w1[c]) + x1*b2f(w1[4+c]);
  #pragma unroll
  for (int c = 0; c < 4; c++) hs[n][c] = hw[c];
  __syncthreads();
  for (int e = n; e < EE; e += 64) nrm[e] = dinv[se[e]] * dinv[de[e]];
  __syncthreads();
  float selfc = di*di;
  float agg[4];
  #pragma unroll
  for (int c = 0; c < 4; c++) agg[c] = hw[c]*selfc;
  for (int e = 0; e < EE; e++){
    if (de[e] == n){
      float w = nrm[e]; int s = se[e];
      #pragma unroll
      for (int c = 0; c < 4; c++) agg[c] += hs[s][c]*w;
    }
  }
  float h1[4];
  #pragma unroll
  for (int c = 0; c < 4; c++) h1[c] = tanh_f(agg[c] + b2f(b1[c]));
  __syncthreads();
  float hw2[2];
  #pragma unroll
  for (int c = 0; c < 2; c++){
    float s = 0.f;
    #pragma unroll
    for (int k = 0; k < 4; k++) s += h1[k]*b2f(w2[k*2+c]);
    hw2[c] = s;
    hs[n][c] = s;
  }
  __syncthreads();
  float agg2[2] = { hw2[0]*selfc, hw2[1]*selfc };
  for (int e = 0; e < EE; e++){
    if (de[e] == n){
      float w = nrm[e]; int s = se[e];
      agg2[0] += hs[s][0]*w;
      agg2[1] += hs[s][1]*w;
    }
  }
  float h2a = tanh_f(agg2[0] + b2f(b2[0]));
  float h2b = tanh_f(agg2[1] + b2f(b2[1]));
  #pragma unroll
  for (int c = 0; c < 2; c++){
    float o = h2a*b2f(cw[c]) + h2b*b2f(cw[2+c]) + b2f(cb[c]);
    res[(size_t)g*128 + n*2 + c] = f2b(o);
  }
}

// ---------------- bf16 transpose ----------------
__global__ __launch_bounds__(256) void transpose_bf16(
    const u16* __restrict__ in, u16* __restrict__ out, int R, int C)
{
  __shared__ u16 tile[32][33];
  int c0 = blockIdx.x*32, r0 = blockIdx.y*32;
  for (int i = threadIdx.y; i < 32; i += 8)
    tile[i][threadIdx.x] = in[(size_t)(r0+i)*C + c0 + threadIdx.x];
  __syncthreads();
  for (int i = threadIdx.y; i < 32; i += 8)
    out[(size_t)(c0+i)*R + r0 + threadIdx.x] = tile[threadIdx.x][i];
}

// ---------------- GEMM NT ----------------
__global__ __launch_bounds__(256) void gemm_nt(
    const u16* __restrict__ A, const u16* __restrict__ Bm,
    const u16* __restrict__ bias, void* __restrict__ C,
    int M, int N, int K, int relu, int permA, int permC,
    const int* __restrict__ outflag)
{
  const int wave = threadIdx.x >> 6;
  const int lane = threadIdx.x & 63;
  const int wm = wave >> 1, wn = wave & 1;
  const int q = lane >> 4, lr = lane & 15;
  const int mBase = blockIdx.y*128 + wm*64;
  const int nBase = blockIdx.x*128 + wn*64;
  f32x4 acc[4][4] = {};
  const u16* ap[4]; const u16* bp[4];
  #pragma unroll
  for (int i = 0; i < 4; i++){
    ap[i] = A + (size_t)prow(mBase + i*16 + lr, permA)*K + q*8;
    bp[i] = Bm + (size_t)(nBase + i*16 + lr)*K + q*8;
  }
  for (int kb = 0; kb < K; kb += 32){
    bf16x8 av[4], bv[4];
    #pragma unroll
    for (int i = 0; i < 4; i++){
      av[i] = *(const bf16x8*)ap[i]; bv[i] = *(const bf16x8*)bp[i];
      ap[i] += 32; bp[i] += 32;
    }
    #pragma unroll
    for (int mi = 0; mi < 4; mi++)
      #pragma unroll
      for (int ni = 0; ni < 4; ni++)
        acc[mi][ni] = __builtin_amdgcn_mfma_f32_16x16x32_bf16(av[mi], bv[ni], acc[mi][ni], 0, 0, 0);
  }
  const int of32 = outflag ? *outflag : 0;
  #pragma unroll
  for (int ni = 0; ni < 4; ni++){
    int col = nBase + ni*16 + lr;
    float bb = bias ? b2f(bias[col]) : 0.f;
    #pragma unroll
    for (int mi = 0; mi < 4; mi++){
      #pragma unroll
      for (int r = 0; r < 4; r++){
        int row = prow(mBase + mi*16 + q*4 + r, permC);
        float v = acc[mi][ni][r] + bb;
        if (relu) v = fmaxf(v, 0.f);
        size_t idx = (size_t)row*N + col;
        if (of32) ((float*)C)[idx] = v;
        else      ((u16*)C)[idx]   = f2b(v);
      }
    }
  }
}

// ---------------- pipelined 2-layer encoder recurrence ----------------
// 256 WGs x 64 thr. wids 0-127 = layer 0 (round-4 structure). wids 128-255 =
// layer 1, gi computed on the fly. ROUND-8 CHANGE: L1's h1-independent work
// (aI = h0[t] @ wih1, gated by c0[t] which L0's lead makes free) executes
// BEFORE the c1[t-1] spin, so the h1->h1 critical chain holds only the
// aH half -> pipeline period ~= L0's single-layer step. r/z gates share
// accumulators across the two halves; the n-gate keeps aI2/aH2 separate
// (reference: n = tanh(gi_n + r * gh_n)). XCD-paired mapping keeps per-XCD
// weights at 18MB/8 = 2.25MB (L2-resident).
__global__ __launch_bounds__(64) void enc_pipe(
    const u16* __restrict__ gi,    // [TT*32,3072] t-major (bih0 incl)
    const u16* __restrict__ wih1,  // [3072,1024]
    const u16* __restrict__ whh0,  // [3072,1024]
    const u16* __restrict__ whh1,  // [3072,1024]
    const u16* __restrict__ bih1, const u16* __restrict__ bhh0,
    const u16* __restrict__ bhh1,
    u16* __restrict__ h0seq,       // [TT*32,1024] t-major
    u16* __restrict__ h1seq,       // [TT*32,1024] t-major (gi dead prefix)
    int* __restrict__ cnt)         // [16*TT]: L0 = [0,8*TT), L1 = [8*TT,16*TT)
{
  const int wid = blockIdx.x;
  const int lane = threadIdx.x & 63;
  const int q = lane >> 4, lr = lane & 15;
  const int sub = wid & 7;
  float hreg[4] = {0.f,0.f,0.f,0.f};
  int* c0 = cnt;
  int* c1 = cnt + 8*TT;

  if (wid < 128){
    // ---------- layer 0 (round-4 structure) ----------
    const int jg = wid & 63, half = wid >> 6;
    const int j = jg*16 + lr, bbase = half*16;
    const float bh_r = b2f(bhh0[j]);
    const float bh_z = b2f(bhh0[H8 + j]);
    const float bh_n = b2f(bhh0[2*H8 + j]);
    const u16* wp0 = whh0 + (size_t)(0*H8 + j)*H8 + q*8;
    const u16* wp1 = whh0 + (size_t)(1*H8 + j)*H8 + q*8;
    const u16* wp2 = whh0 + (size_t)(2*H8 + j)*H8 + q*8;
    u16 gpre[12];
    #pragma unroll
    for (int r = 0; r < 4; r++){
      size_t row = (size_t)(bbase + q*4 + r)*H3;
      gpre[r]   = gi[row + j];
      gpre[4+r] = gi[row + H8 + j];
      gpre[8+r] = gi[row + 2*H8 + j];
    }
    for (int t = 0; t < TT; t++){
      if (t > 0) spin128(c0, t - 1);
      float gr_[4], gz_[4], gn_[4];
      #pragma unroll
      for (int r = 0; r < 4; r++){
        gr_[r] = b2f(gpre[r]); gz_[r] = b2f(gpre[4+r]); gn_[r] = b2f(gpre[8+r]);
      }
      f32x4 acc0 = {}, acc1 = {}, acc2 = {};
      if (t > 0){
        const u16* ap = h0seq + (size_t)((t-1)*BSZ + bbase + lr)*H8 + q*8;
        #pragma unroll 8
        for (int kb = 0; kb < 32; kb++){
          const u64* p = (const u64*)(ap + kb*32);
          union { u64 v[2]; bf16x8 b; } A; A.v[0] = aload64(p); A.v[1] = aload64(p+1);
          bf16x8 w0 = *(const bf16x8*)(wp0 + kb*32);
          bf16x8 w1 = *(const bf16x8*)(wp1 + kb*32);
          bf16x8 w2 = *(const bf16x8*)(wp2 + kb*32);
          acc0 = __builtin_amdgcn_mfma_f32_16x16x32_bf16(A.b, w0, acc0, 0,0,0);
          acc1 = __builtin_amdgcn_mfma_f32_16x16x32_bf16(A.b, w1, acc1, 0,0,0);
          acc2 = __builtin_amdgcn_mfma_f32_16x16x32_bf16(A.b, w2, acc2, 0,0,0);
        }
      }
      #pragma unroll
      for (int r = 0; r < 4; r++){
        float rr = sigm(gr_[r] + acc0[r] + bh_r);
        float zz = sigm(gz_[r] + acc1[r] + bh_z);
        float nn = tanh_f(gn_[r] + rr*(acc2[r] + bh_n));
        float hnew = (1.f - zz)*nn + zz*hreg[r];
        hreg[r] = hnew;
        __hip_atomic_store(&h0seq[(size_t)(t*BSZ + bbase + q*4 + r)*H8 + j], f2b(hnew),
                           __ATOMIC_RELAXED, __HIP_MEMORY_SCOPE_AGENT);
      }
      asm volatile("s_waitcnt vmcnt(0)" ::: "memory");
      if (lane == 0)
        __hip_atomic_fetch_add(&c0[sub*TT + t], 1, __ATOMIC_RELAXED, __HIP_MEMORY_SCOPE_AGENT);
      if (t + 1 < TT){
        #pragma unroll
        for (int r = 0; r < 4; r++){
          size_t row = (size_t)((t+1)*BSZ + bbase + q*4 + r)*H3;
          gpre[r]   = gi[row + j];
          gpre[4+r] = gi[row + H8 + j];
          gpre[8+r] = gi[row + 2*H8 + j];
        }
      }
    }
  } else {
    // ---------- layer 1: aI half first (h1-independent), then aH half ----------
    const int wid2 = wid - 128;
    const int jg = wid2 & 63, half = wid2 >> 6;
    const int j = jg*16 + lr, bbase = half*16;
    const float brz_r = b2f(bih1[j])        + b2f(bhh1[j]);        // merged r bias
    const float brz_z = b2f(bih1[H8 + j])   + b2f(bhh1[H8 + j]);   // merged z bias
    const float bin   = b2f(bih1[2*H8 + j]);
    const float bhn   = b2f(bhh1[2*H8 + j]);
    const u16* ip0 = wih1 + (size_t)(0*H8 + j)*H8 + q*8;
    const u16* ip1 = wih1 + (size_t)(1*H8 + j)*H8 + q*8;
    const u16* ip2 = wih1 + (size_t)(2*H8 + j)*H8 + q*8;
    const u16* hp0 = whh1 + (size_t)(0*H8 + j)*H8 + q*8;
    const u16* hp1 = whh1 + (size_t)(1*H8 + j)*H8 + q*8;
    const u16* hp2 = whh1 + (size_t)(2*H8 + j)*H8 + q*8;
    for (int t = 0; t < TT; t++){
      // --- aI half: needs only h0[t]; c0[t] is free once L0 pulls ahead ---
      spin128(c0, t);
      f32x4 accR = {}, accZ = {}, aI2 = {}, aH2 = {};
      const u16* a0p = h0seq + (size_t)(t*BSZ + bbase + lr)*H8 + q*8;
      #pragma unroll 8
      for (int kb = 0; kb < 32; kb++){
        const u64* p0 = (const u64*)(a0p + kb*32);
        union { u64 v[2]; bf16x8 b; } A0; A0.v[0] = aload64(p0); A0.v[1] = aload64(p0+1);
        bf16x8 i0 = *(const bf16x8*)(ip0 + kb*32);
        bf16x8 i1 = *(const bf16x8*)(ip1 + kb*32);
        bf16x8 i2 = *(const bf16x8*)(ip2 + kb*32);
        accR = __builtin_amdgcn_mfma_f32_16x16x32_bf16(A0.b, i0, accR, 0,0,0);
        accZ = __builtin_amdgcn_mfma_f32_16x16x32_bf16(A0.b, i1, accZ, 0,0,0);
        aI2  = __builtin_amdgcn_mfma_f32_16x16x32_bf16(A0.b, i2, aI2,  0,0,0);
      }
      // --- aH half: the true h1[t-1] -> h1[t] critical chain ---
      if (t > 0){
        spin128(c1, t - 1);
        const u16* a1p = h1seq + (size_t)((t-1)*BSZ + bbase + lr)*H8 + q*8;
        #pragma unroll 8
        for (int kb = 0; kb < 32; kb++){
          const u64* p1 = (const u64*)(a1p + kb*32);
          union { u64 v[2]; bf16x8 b; } A1; A1.v[0] = aload64(p1); A1.v[1] = aload64(p1+1);
          bf16x8 h0v = *(const bf16x8*)(hp0 + kb*32);
          bf16x8 h1v = *(const bf16x8*)(hp1 + kb*32);
          bf16x8 h2v = *(const bf16x8*)(hp2 + kb*32);
          accR = __builtin_amdgcn_mfma_f32_16x16x32_bf16(A1.b, h0v, accR, 0,0,0);
          accZ = __builtin_amdgcn_mfma_f32_16x16x32_bf16(A1.b, h1v, accZ, 0,0,0);
          aH2  = __builtin_amdgcn_mfma_f32_16x16x32_bf16(A1.b, h2v, aH2,  0,0,0);
        }
      }
      #pragma unroll
      for (int r = 0; r < 4; r++){
        float rr = sigm(accR[r] + brz_r);
        float zz = sigm(accZ[r] + brz_z);
        float nn = tanh_f(aI2[r] + bin + rr*(aH2[r] + bhn));
        float hnew = (1.f - zz)*nn + zz*hreg[r];
        hreg[r] = hnew;
        __hip_atomic_store(&h1seq[(size_t)(t*BSZ + bbase + q*4 + r)*H8 + j], f2b(hnew),
                           __ATOMIC_RELAXED, __HIP_MEMORY_SCOPE_AGENT);
      }
      asm volatile("s_waitcnt vmcnt(0)" ::: "memory");
      if (lane == 0)
        __hip_atomic_fetch_add(&c1[sub*TT + t], 1, __ATOMIC_RELAXED, __HIP_MEMORY_SCOPE_AGENT);
    }
  }
}

// ---------------- decoder GRU recurrence (H=128), round-4 proven ----------------
__global__ __launch_bounds__(256) void dec_rec(
    const u16* __restrict__ gi,   // [TT*32, 384] t-major (bih included)
    const u16* __restrict__ whh,  // [384, 128]
    const u16* __restrict__ bhh,  // [384]
    u16* __restrict__ seq)        // out [TT*32, 128] t-major
{
  __shared__ u16 hlds[16*136];
  const int bb = blockIdx.x*16;
  const int tid = threadIdx.x;
  const int w = tid >> 6, lane = tid & 63, q = lane >> 4, lr = lane & 15;
  bf16x8 wreg[3][2][4];
  #pragma unroll
  for (int g2 = 0; g2 < 3; g2++)
    #pragma unroll
    for (int nt = 0; nt < 2; nt++){
      int jj = g2*128 + w*32 + nt*16 + lr;
      #pragma unroll
      for (int kb = 0; kb < 4; kb++)
        wreg[g2][nt][kb] = *(const bf16x8*)(whh + (size_t)jj*128 + kb*32 + q*8);
    }
  float bh[3][2];
  #pragma unroll
  for (int g2 = 0; g2 < 3; g2++)
    #pragma unroll
    for (int nt = 0; nt < 2; nt++)
      bh[g2][nt] = b2f(bhh[g2*128 + w*32 + nt*16 + lr]);
  float hreg[2][4] = {};
  u16 gpre[3][2][4];
  #pragma unroll
  for (int r = 0; r < 4; r++){
    size_t row = (size_t)(bb + q*4 + r)*384;
    #pragma unroll
    for (int nt = 0; nt < 2; nt++){
      int jj = w*32 + nt*16 + lr;
      #pragma unroll
      for (int g2 = 0; g2 < 3; g2++)
        gpre[g2][nt][r] = gi[row + g2*128 + jj];
    }
  }
  __syncthreads();
  for (int t = 0; t < TT; t++){
    float gif[3][2][4];
    #pragma unroll
    for (int g2 = 0; g2 < 3; g2++)
      #pragma unroll
      for (int nt = 0; nt < 2; nt++)
        #pragma unroll
        for (int r = 0; r < 4; r++)
          gif[g2][nt][r] = b2f(gpre[g2][nt][r]);
    f32x4 acc[3][2] = {};
    if (t > 0){
      #pragma unroll
      for (int kb = 0; kb < 4; kb++){
        bf16x8 a = *(const bf16x8*)(hlds + lr*136 + kb*32 + q*8);
        #pragma unroll
        for (int g2 = 0; g2 < 3; g2++)
          #pragma unroll
          for (int nt = 0; nt < 2; nt++)
            acc[g2][nt] = __builtin_amdgcn_mfma_f32_16x16x32_bf16(a, wreg[g2][nt][kb], acc[g2][nt], 0,0,0);
      }
    }
    __syncthreads();
    #pragma unroll
    for (int nt = 0; nt < 2; nt++)
      #pragma unroll
      for (int r = 0; r < 4; r++){
        int jj = w*32 + nt*16 + lr;
        int b = bb + q*4 + r;
        float rr = sigm(gif[0][nt][r] + acc[0][nt][r] + bh[0][nt]);
        float zz = sigm(gif[1][nt][r] + acc[1][nt][r] + bh[1][nt]);
        float nn = tanh_f(gif[2][nt][r] + rr*(acc[2][nt][r] + bh[2][nt]));
        float hnew = (1.f - zz)*nn + zz*hreg[nt][r];
        hreg[nt][r] = hnew;
        u16 hb = f2b(hnew);
        hlds[(q*4 + r)*136 + jj] = hb;
        seq[(size_t)(t*BSZ + b)*128 + jj] = hb;
      }
    if (t + 1 < TT){
      #pragma unroll
      for (int r = 0; r < 4; r++){
        size_t row = (size_t)((t+1)*BSZ + bb + q*4 + r)*384;
        #pragma unroll
        for (int nt = 0; nt < 2; nt++){
          int jj = w*32 + nt*16 + lr;
          #pragma unroll
          for (int g2 = 0; g2 < 3; g2++)
            gpre[g2][nt][r] = gi[row + g2*128 + jj];
        }
      }
    }
    __syncthreads();
  }
}

extern "C" void kernel_launch(void* const* d_in, const int* in_sizes, int n_in,
                              void* d_out, int out_size, void* d_ws, size_t ws_size,
                              hipStream_t stream)
{
  const void* x    = d_in[0];
  const int* ei    = (const int*)d_in[1];

  const size_t NEED = (size_t)164 << 20;
  if (ws_size < NEED) return;
  char* wsb = (char*)d_ws;
  const size_t KB = 1024, MB = 1024*1024;

  int* syncv = (int*)wsb;                       // 32 KB: 16x512 counters
  int* flag  = (int*)(wsb + 40*KB);
  u16* gw1_c  = (u16*)(wsb + 1*MB + 0);
  u16* gb1_c  = (u16*)(wsb + 1*MB + 64);
  u16* gw2_c  = (u16*)(wsb + 1*MB + 128);
  u16* gb2_c  = (u16*)(wsb + 1*MB + 192);
  u16* gcw_c  = (u16*)(wsb + 1*MB + 256);
  u16* gcb_c  = (u16*)(wsb + 1*MB + 320);
  u16* efb_c  = (u16*)(wsb + 1*MB + 4*KB);
  u16* ebih_c = (u16*)(wsb + 1*MB + 8*KB);
  u16* ebhh_c = (u16*)(wsb + 1*MB + 24*KB);
  u16* dfb_c  = (u16*)(wsb + 1*MB + 40*KB);
  u16* dbih_c = (u16*)(wsb + 1*MB + 45*KB);
  u16* dbhh_c = (u16*)(wsb + 1*MB + 47*KB);
  u16* dlb_c  = (u16*)(wsb + 1*MB + 49*KB);
  u16* wT3    = (u16*)(wsb + 1*MB + 64*KB);
  u16* dlw_c  = (u16*)(wsb + 1*MB + 128*KB);
  u16* efw_c  = (u16*)(wsb + 1*MB + 192*KB);
  u16* wT1    = (u16*)(wsb + 1*MB + 448*KB);
  u16* dfw_c  = (u16*)(wsb + 2*MB);
  u16* wT2    = (u16*)(wsb + 4*MB);
  u16* dwih0_c= (u16*)(wsb + 6*MB);
  u16* dwih1_c= (u16*)(wsb + 7*MB);
  u16* dwhh_c = (u16*)(wsb + 7*MB + 128*KB);
  u16* ewih_c = (u16*)(wsb + 8*MB);             // 12MB [2,3072,1024]
  u16* ewhh_c = (u16*)(wsb + 20*MB);            // 12MB
  u16* res    = (u16*)(wsb + 32*MB);            // 4MB  GCN out -> seq3
  u16* bufA   = (u16*)(wsb + 36*MB);            // 32MB x0 -> h0seq -> seq4
  u16* bufC   = (u16*)(wsb + 68*MB);            // 96MB gi0; h1seq prefix; d0; giD
  u16* x_c    = bufC;                           // 4MB alias (dead before gi0)
  u16* h1seq  = bufC;                           // [TT*32,1024] in gi0 dead prefix
  u16* d0     = (u16*)(wsb + 102*MB);           // 32MB (inside bufC, after h1seq)
  u16* giD    = (u16*)(wsb + 136*MB);           // 12MB (inside bufC tail)

  hipMemsetAsync(syncv, 0, 32*KB, stream);
  detect_dtype<<<1, 256, 0, stream>>>(x, flag);

  auto cvt = [&](int idx, u16* dst, int n){
    cvt_bf16<<<(n + 255)/256, 256, 0, stream>>>(d_in[idx], dst, n, flag);
  };
  cvt(0,  x_c,     GG*NNODE*2);
  cvt(2,  gw1_c, 8);  cvt(3, gb1_c, 4);  cvt(4, gw2_c, 8);
  cvt(5,  gb2_c, 2);  cvt(6, gcw_c, 4);  cvt(7, gcb_c, 2);
  cvt(8,  efw_c,   128*1024);   cvt(9,  efb_c, 1024);
  cvt(10, ewih_c,  2*3072*1024);
  cvt(11, ewhh_c,  2*3072*1024);
  cvt(12, ebih_c,  2*3072);     cvt(13, ebhh_c, 2*3072);
  cvt(14, dfw_c,   1024*1024);  cvt(15, dfb_c, 1024);
  cvt(16, dwih0_c, 384*1024);   cvt(17, dwih1_c, 384*128);
  cvt(18, dwhh_c,  2*384*128);
  cvt(19, dbih_c,  2*384);      cvt(20, dbhh_c, 2*384);
  cvt(21, dlw_c,   128*128);    cvt(22, dlb_c, 128);

  transpose_bf16<<<dim3(1024/32, 128/32),  dim3(32,8), 0, stream>>>(efw_c, wT1, 128, 1024);
  transpose_bf16<<<dim3(1024/32, 1024/32), dim3(32,8), 0, stream>>>(dfw_c, wT2, 1024, 1024);
  transpose_bf16<<<dim3(128/32, 128/32),   dim3(32,8), 0, stream>>>(dlw_c, wT3, 128, 128);

  // GCN -> res [GG,128] (b-major)
  gcn_kernel<<<GG, 64, 0, stream>>>(x_c, ei, gw1_c, gb1_c, gw2_c, gb2_c, gcw_c, gcb_c, res);

  // encoder fl: x0 = relu(res @ efw + efb) -> bufA [t][b]
  gemm_nt<<<dim3(1024/128, GG/128), 256, 0, stream>>>(res, wT1, efb_c, bufA, GG, 1024, 128, 1, 0, 1, nullptr);
  // enc layer-0 gi: x0 @ ewih0 -> bufC [t][b][3072]
  gemm_nt<<<dim3(3072/128, GG/128), 256, 0, stream>>>(bufA, ewih_c, ebih_c, bufC, GG, 3072, 1024, 0, 1, 1, nullptr);
  // pipelined both-layer recurrence: h0 -> bufA, h1 -> h1seq (gi dead prefix)
  enc_pipe<<<256, 64, 0, stream>>>(bufC, ewih_c + 3072*1024, ewhh_c, ewhh_c + 3072*1024,
                                   ebih_c + 3072, ebhh_c, ebhh_c + 3072,
                                   bufA, h1seq, syncv);

  // decoder fl: d0 = relu(h1seq @ dfw + dfb) -> d0 [t][b]
  gemm_nt<<<dim3(1024/128, GG/128), 256, 0, stream>>>(h1seq, wT2, dfb_c, d0, GG, 1024, 1024, 1, 1, 1, nullptr);
  // dec layer-0 gi: d0 @ dwih0 -> giD [t][b][384]
  gemm_nt<<<dim3(384/128, GG/128), 256, 0, stream>>>(d0, dwih0_c, dbih_c, giD, GG, 384, 1024, 0, 1, 1, nullptr);
  dec_rec<<<2, 256, 0, stream>>>(giD, dwhh_c, dbhh_c, res);
  // dec layer-1 gi: seq3 @ dwih1 -> giD
  gemm_nt<<<dim3(384/128, GG/128), 256, 0, stream>>>(res, dwih1_c, dbih_c + 384, giD, GG, 384, 128, 0, 1, 1, nullptr);
  dec_rec<<<2, 256, 0, stream>>>(giD, dwhh_c + 384*128, dbhh_c + 384, bufA);

  // final linear: seq4 [t][b] -> d_out rows b*TT+t (bf16 or f32 per dtype)
  gemm_nt<<<dim3(128/128, GG/128), 256, 0, stream>>>(bufA, wT3, dlb_c, d_out, GG, 128, 128, 0, 1, 0, flag);
}